// Round 3
// baseline (1160.607 us; speedup 1.0000x reference)
//
#include <hip/hip_runtime.h>

#define NUM_USERS 100000
#define NUM_ITEMS 50000
#define NNODES    150000
#define EMB       64
#define NEDGES    4800000
#define BATCH     4096
#define NB        586           // ceil(NNODES/256) — scan blocks AND row-buckets
#define NSLICE    8
#define SLICE_CAP 1600          // per (bucket,slice) capacity; mean ~1024

// cur init: concat(user_emb, item_emb), float4 vectorized.
__global__ void init_kernel(const float* __restrict__ user_emb,
                            const float* __restrict__ item_emb,
                            float* __restrict__ cur) {
    long i = (long)blockIdx.x * blockDim.x + threadIdx.x;   // float4 units
    const long n4 = (long)NNODES * EMB / 4;
    if (i >= n4) return;
    const long nu4 = (long)NUM_USERS * EMB / 4;
    float4 v = (i < nu4) ? ((const float4*)user_emb)[i]
                         : ((const float4*)item_emb)[i - nu4];
    ((float4*)cur)[i] = v;
}

// --- CSR build ---------------------------------------------------------

// Pass A: bin edges by (row>>8, blockIdx&7) into fixed slots; fused row histogram.
// pack = (rowLocal<<18) | col  (col<2^18, rowLocal<256)
__global__ void binA_kernel(const int* __restrict__ rows, const int* __restrict__ cols,
                            const float* __restrict__ vals,
                            int* __restrict__ counts, int* __restrict__ bfill,
                            int2* __restrict__ tmp) {
    int e = blockIdx.x * blockDim.x + threadIdx.x;
    if (e >= NEDGES) return;
    int r = rows[e];
    atomicAdd(&counts[r], 1);                       // fused histogram
    int b = r >> 8;
    int slice = blockIdx.x & (NSLICE - 1);          // XCD proxy (perf heuristic only)
    int slot = b * NSLICE + slice;
    int idx = atomicAdd(&bfill[slot], 1);
    tmp[(long)slot * SLICE_CAP + idx] = make_int2(((r & 255) << 18) | cols[e],
                                                  __float_as_int(vals[e]));
}

// per-256-block sums of counts
__global__ void scanA(const int* __restrict__ counts, int* __restrict__ blkSums) {
    int i = blockIdx.x * 256 + threadIdx.x;
    int c = (i < NNODES) ? counts[i] : 0;
    #pragma unroll
    for (int d = 32; d > 0; d >>= 1) c += __shfl_down(c, d, 64);
    __shared__ int wsum[4];
    int lane = threadIdx.x & 63, w = threadIdx.x >> 6;
    if (lane == 0) wsum[w] = c;
    __syncthreads();
    if (threadIdx.x == 0)
        blkSums[blockIdx.x] = wsum[0] + wsum[1] + wsum[2] + wsum[3];
}

// exclusive scan of blkSums in place (single wave, chunks of 64 with carry)
__global__ void scanB(int* __restrict__ blk) {
    int lane = threadIdx.x;
    int carry = 0;
    for (int base = 0; base < NB; base += 64) {
        int i = base + lane;
        int orig = (i < NB) ? blk[i] : 0;
        int x = orig;
        #pragma unroll
        for (int d = 1; d < 64; d <<= 1) {
            int t = __shfl_up(x, d, 64);
            if (lane >= d) x += t;
        }
        int total = __shfl(x, 63, 64);
        if (i < NB) blk[i] = x - orig + carry;   // exclusive
        carry += total;
    }
}

// per-block exclusive scan + block offset -> rowPtr
__global__ void scanC(const int* __restrict__ counts, const int* __restrict__ blkOff,
                      int* __restrict__ rowPtr) {
    int i = blockIdx.x * 256 + threadIdx.x;
    int c = (i < NNODES) ? counts[i] : 0;
    int lane = threadIdx.x & 63, w = threadIdx.x >> 6;
    int x = c;
    #pragma unroll
    for (int d = 1; d < 64; d <<= 1) {
        int t = __shfl_up(x, d, 64);
        if (lane >= d) x += t;
    }
    __shared__ int wsum[4];
    if (lane == 63) wsum[w] = x;
    __syncthreads();
    int off = blkOff[blockIdx.x];
    for (int k = 0; k < w; ++k) off += wsum[k];
    if (i < NNODES) rowPtr[i] = off + x - c;     // exclusive
    if (blockIdx.x == 0 && threadIdx.x == 0) rowPtr[NNODES] = NEDGES;
}

// Pass B: one workgroup per bucket -> final CSR positions via LDS counters.
// Destination window per bucket ~64 KB contiguous -> L2-resident writes.
__global__ void __launch_bounds__(256) binB_kernel(const int* __restrict__ bfill,
                                                   const int2* __restrict__ tmp,
                                                   const int* __restrict__ rowPtr,
                                                   int2* __restrict__ csr) {
    int bucket = blockIdx.x;
    int rowBase = bucket << 8;
    __shared__ int rp[256];
    __shared__ int fill[256];
    int i = rowBase + (int)threadIdx.x;
    rp[threadIdx.x] = rowPtr[i < NNODES ? i : NNODES];
    fill[threadIdx.x] = 0;
    __syncthreads();
    for (int s = 0; s < NSLICE; ++s) {
        int slot = bucket * NSLICE + s;
        int cnt = bfill[slot];
        const int2* src = tmp + (long)slot * SLICE_CAP;
        for (int k = threadIdx.x; k < cnt; k += 256) {
            int2 p = src[k];
            int rL  = p.x >> 18;
            int col = p.x & 0x3FFFF;
            int pos = rp[rL] + atomicAdd(&fill[rL], 1);
            csr[pos] = make_int2(col, p.y);
        }
    }
}

// --- SpMM: one 16-lane quarter-wave per row, float4 slice per lane ------

__global__ void spmm_csr(const int* __restrict__ rowPtr, const int2* __restrict__ csr,
                         const float* __restrict__ cur, float* __restrict__ nxt) {
    int gtid = blockIdx.x * blockDim.x + threadIdx.x;
    int row = gtid >> 4;
    int t   = gtid & 15;
    if (row >= NNODES) return;
    int beg = rowPtr[row], end = rowPtr[row + 1];
    float4 s = make_float4(0.f, 0.f, 0.f, 0.f);
    int e = beg;
    for (; e + 3 < end; e += 4) {            // 4x unroll for gather ILP
        int2 p0 = csr[e];
        int2 p1 = csr[e + 1];
        int2 p2 = csr[e + 2];
        int2 p3 = csr[e + 3];
        float4 x0 = ((const float4*)(cur + (long)p0.x * EMB))[t];
        float4 x1 = ((const float4*)(cur + (long)p1.x * EMB))[t];
        float4 x2 = ((const float4*)(cur + (long)p2.x * EMB))[t];
        float4 x3 = ((const float4*)(cur + (long)p3.x * EMB))[t];
        float v0 = __int_as_float(p0.y), v1 = __int_as_float(p1.y);
        float v2 = __int_as_float(p2.y), v3 = __int_as_float(p3.y);
        s.x += v0 * x0.x; s.y += v0 * x0.y; s.z += v0 * x0.z; s.w += v0 * x0.w;
        s.x += v1 * x1.x; s.y += v1 * x1.y; s.z += v1 * x1.z; s.w += v1 * x1.w;
        s.x += v2 * x2.x; s.y += v2 * x2.y; s.z += v2 * x2.z; s.w += v2 * x2.w;
        s.x += v3 * x3.x; s.y += v3 * x3.y; s.z += v3 * x3.z; s.w += v3 * x3.w;
    }
    for (; e < end; ++e) {
        int2 p = csr[e];
        float v = __int_as_float(p.y);
        float4 x = ((const float4*)(cur + (long)p.x * EMB))[t];
        s.x += v * x.x; s.y += v * x.y; s.z += v * x.z; s.w += v * x.w;
    }
    ((float4*)nxt)[(long)row * (EMB / 4) + t] = s;
}

// One wave per batch element; lane = embedding dim.
// final = (emb + l1 + l2 + l3)/4  -> dot scaled by 1/16.
__global__ void score_kernel(const int* __restrict__ users,
                             const int* __restrict__ pos_items,
                             const int* __restrict__ neg_items,
                             const float* __restrict__ uemb,
                             const float* __restrict__ iemb,
                             const float* __restrict__ l1,
                             const float* __restrict__ l2,
                             const float* __restrict__ l3,
                             float* __restrict__ out) {
    int gtid = blockIdx.x * blockDim.x + threadIdx.x;
    int wave = gtid >> 6;
    int lane = threadIdx.x & 63;
    if (wave >= BATCH) return;
    int u = users[wave];
    int p = pos_items[wave];
    int n = neg_items[wave];
    long U = (long)u * EMB + lane;
    long P = (long)(p + NUM_USERS) * EMB + lane;
    long N = (long)(n + NUM_USERS) * EMB + lane;
    float ue = uemb[(long)u * EMB + lane] + l1[U] + l2[U] + l3[U];
    float pe = iemb[(long)p * EMB + lane] + l1[P] + l2[P] + l3[P];
    float ne = iemb[(long)n * EMB + lane] + l1[N] + l2[N] + l3[N];
    float ps = ue * pe;
    float ns = ue * ne;
    #pragma unroll
    for (int off = 32; off > 0; off >>= 1) {
        ps += __shfl_down(ps, off, 64);
        ns += __shfl_down(ns, off, 64);
    }
    if (lane == 0) {
        out[wave]         = ps * 0.0625f;
        out[BATCH + wave] = ns * 0.0625f;
    }
}

extern "C" void kernel_launch(void* const* d_in, const int* in_sizes, int n_in,
                              void* d_out, int out_size, void* d_ws, size_t ws_size,
                              hipStream_t stream) {
    const int*   users = (const int*)d_in[0];
    const int*   pos   = (const int*)d_in[1];
    const int*   neg   = (const int*)d_in[2];
    const int*   rows  = (const int*)d_in[3];
    const int*   cols  = (const int*)d_in[4];
    const float* vals  = (const float*)d_in[5];
    const float* uemb  = (const float*)d_in[6];
    const float* iemb  = (const float*)d_in[7];
    float* out = (float*)d_out;

    const size_t bufElems = (size_t)NNODES * EMB;       // 9.6M floats = 38.4 MB
    float* bufA   = (float*)d_ws;                       // l0 (emb), later l3
    float* bufB   = bufA + bufElems;                    // l1   (tmp aliases B..C)
    float* bufC   = bufB + bufElems;                    // l2
    int2*  csr    = (int2*)(bufC + bufElems);           // NEDGES int2
    int*   rowPtr = (int*)(csr + NEDGES);               // 150016
    int*   counts = rowPtr + 150016;                    // NNODES
    int*   bfill  = counts + NNODES;                    // NB*NSLICE (4688) pad 4736
    int*   blkSums= bfill + 4736;                       // NB pad 1024
    int2*  tmp    = (int2*)bufB;                        // NB*NSLICE*SLICE_CAP int2 = 60 MB
                                                        // (fits in bufB+bufC; consumed
                                                        //  by binB before spmm writes)

    // zero counts + bfill in one shot (they're contiguous)
    hipMemsetAsync(counts, 0, (NNODES + 4736) * sizeof(int), stream);

    // CSR build: bin (fused hist) -> scan -> resolve
    binA_kernel<<<(NEDGES + 255) / 256, 256, 0, stream>>>(rows, cols, vals, counts, bfill, tmp);
    scanA<<<NB, 256, 0, stream>>>(counts, blkSums);
    scanB<<<1, 64, 0, stream>>>(blkSums);
    scanC<<<NB, 256, 0, stream>>>(counts, blkSums, rowPtr);
    binB_kernel<<<NB, 256, 0, stream>>>(bfill, tmp, rowPtr, csr);

    // init l0
    const long n4 = (long)bufElems / 4;
    init_kernel<<<(int)((n4 + 255) / 256), 256, 0, stream>>>(uemb, iemb, bufA);

    // 3 propagation layers: l1=A·l0, l2=A·l1, l3=A·l2 (l3 overwrites l0)
    const long nth = (long)NNODES * 16;
    const int  spmmGrid = (int)((nth + 255) / 256);
    spmm_csr<<<spmmGrid, 256, 0, stream>>>(rowPtr, csr, bufA, bufB);
    spmm_csr<<<spmmGrid, 256, 0, stream>>>(rowPtr, csr, bufB, bufC);
    spmm_csr<<<spmmGrid, 256, 0, stream>>>(rowPtr, csr, bufC, bufA);

    score_kernel<<<(BATCH * 64) / 256, 256, 0, stream>>>(users, pos, neg,
                                                         uemb, iemb, bufB, bufC, bufA, out);
}